// Round 1
// baseline (205.189 us; speedup 1.0000x reference)
//
#include <hip/hip_runtime.h>

#define NCB 32
#define KK 16
#define DD 128
#define IN_F 4096
#define OUT_F 2048
#define NTOK 2048

// Kernel 1: lut[c][k][o] = sum_d centroids[c][k][d] * weight[c][d][o]
// grid (OUT_F/256, NCB), block 256
__global__ __launch_bounds__(256) void lut_kernel(const float* __restrict__ centroids,
                                                  const float* __restrict__ weight,
                                                  float* __restrict__ lut) {
    const int c = blockIdx.y;
    const int o = blockIdx.x * 256 + threadIdx.x;
    __shared__ float cent[KK * DD];  // 8 KB
    const float* cbase = centroids + c * KK * DD;
    for (int i = threadIdx.x; i < KK * DD; i += 256)
        cent[i] = cbase[i];
    __syncthreads();
    float acc[KK];
#pragma unroll
    for (int k = 0; k < KK; ++k) acc[k] = 0.f;
    const float* wbase = weight + (size_t)c * DD * OUT_F + o;
    for (int d = 0; d < DD; ++d) {
        float w = wbase[(size_t)d * OUT_F];
#pragma unroll
        for (int k = 0; k < KK; ++k) acc[k] += cent[k * DD + d] * w;
    }
    float* lbase = lut + (size_t)c * KK * OUT_F + o;
#pragma unroll
    for (int k = 0; k < KK; ++k) lbase[(size_t)k * OUT_F] = acc[k];
}

// Kernel 2: per-token distances -> argmin -> gather-sum of lut rows + bias
// grid NTOK, block 256
__global__ __launch_bounds__(256) void token_kernel(const float* __restrict__ x,
                                                    const float* __restrict__ centroids,
                                                    const float* __restrict__ lut,
                                                    const float* __restrict__ bias,
                                                    float* __restrict__ out) {
    const int t = blockIdx.x;
    __shared__ float xs[IN_F];          // 16 KB
    __shared__ float dproxy[NCB * KK];  // 2 KB
    __shared__ int smidx[NCB];

    // stage x[t] into LDS with float4 loads
    {
        const float4* xg = (const float4*)(x + (size_t)t * IN_F);
        float4* xs4 = (float4*)xs;
        for (int i = threadIdx.x; i < IN_F / 4; i += 256)
            xs4[i] = xg[i];
    }
    __syncthreads();

    // distance proxies: c2 - 2*dot  (argmin-equivalent to euclidean dist)
    for (int p = threadIdx.x; p < NCB * KK; p += 256) {
        const int c = p >> 4;
        const float4* ce = (const float4*)(centroids + (size_t)p * DD);
        const float4* xv = (const float4*)(xs + c * DD);
        float dot = 0.f, c2 = 0.f;
#pragma unroll
        for (int i = 0; i < DD / 4; ++i) {
            float4 cv = ce[i];
            float4 xx = xv[i];
            dot += cv.x * xx.x + cv.y * xx.y + cv.z * xx.z + cv.w * xx.w;
            c2  += cv.x * cv.x + cv.y * cv.y + cv.z * cv.z + cv.w * cv.w;
        }
        dproxy[p] = c2 - 2.f * dot;
    }
    __syncthreads();

    // per-codebook argmin (first-index tie-break, matches jnp.argmin)
    if (threadIdx.x < NCB) {
        const float* dp = dproxy + threadIdx.x * KK;
        float best = dp[0];
        int bi = 0;
#pragma unroll
        for (int k = 1; k < KK; ++k) {
            float v = dp[k];
            if (v < best) { best = v; bi = k; }
        }
        smidx[threadIdx.x] = bi;
    }
    __syncthreads();

    // gather-sum: out[t, :] = bias + sum_c lut[c, idx[c], :]
    const float4* b4 = (const float4*)bias;
    float4 acc0 = b4[threadIdx.x];
    float4 acc1 = b4[threadIdx.x + 256];
#pragma unroll 4
    for (int c = 0; c < NCB; ++c) {
        const float4* l4 = (const float4*)(lut + ((size_t)c * KK + smidx[c]) * OUT_F);
        float4 v0 = l4[threadIdx.x];
        float4 v1 = l4[threadIdx.x + 256];
        acc0.x += v0.x; acc0.y += v0.y; acc0.z += v0.z; acc0.w += v0.w;
        acc1.x += v1.x; acc1.y += v1.y; acc1.z += v1.z; acc1.w += v1.w;
    }
    float4* o4 = (float4*)(out + (size_t)t * OUT_F);
    o4[threadIdx.x] = acc0;
    o4[threadIdx.x + 256] = acc1;
}

extern "C" void kernel_launch(void* const* d_in, const int* in_sizes, int n_in,
                              void* d_out, int out_size, void* d_ws, size_t ws_size,
                              hipStream_t stream) {
    const float* x         = (const float*)d_in[0];  // [2,1024,4096]
    const float* centroids = (const float*)d_in[1];  // [32,16,128]
    const float* weight    = (const float*)d_in[2];  // [32,128,2048]
    // d_in[3] = inverse_temperature_logit — numerically irrelevant (STE forward)
    const float* bias      = (const float*)d_in[4];  // [2048]
    float* out = (float*)d_out;                      // [2048, 2048] fp32
    float* lut = (float*)d_ws;                       // 32*16*2048 fp32 = 4 MB

    lut_kernel<<<dim3(OUT_F / 256, NCB), 256, 0, stream>>>(centroids, weight, lut);
    token_kernel<<<NTOK, 256, 0, stream>>>(x, centroids, lut, bias, out);
}

// Round 2
// 155.235 us; speedup vs baseline: 1.3218x; 1.3218x over previous
//
#include <hip/hip_runtime.h>

#define NCB 32
#define KK 16
#define DD 128
#define IN_F 4096
#define OUT_F 2048
#define NTOK 2048

// ---------------- K1: lut[c][k][o] = sum_d cent[c][k][d] * W[c][d][o] ----------------
// grid (OUT_F/64, NCB) = (32, 32), block 256. Threads: o = tid%64, dgroup = tid/64 (32 d's each).
__global__ __launch_bounds__(256) void lut_kernel(const float* __restrict__ centroids,
                                                  const float* __restrict__ weight,
                                                  float* __restrict__ lut,
                                                  float* __restrict__ c2out) {
    const int c = blockIdx.y;
    const int o0 = blockIdx.x * 64;
    const int lane_o = threadIdx.x & 63;
    const int dg = threadIdx.x >> 6;  // wave id: d-range uniform per wave
    __shared__ float cent[KK * DD];     // 8 KB
    __shared__ float part[4][KK][64];   // 16 KB

    const float4* cbase = (const float4*)(centroids + (size_t)c * KK * DD);
    float4* cs4 = (float4*)cent;
    for (int i = threadIdx.x; i < KK * DD / 4; i += 256) cs4[i] = cbase[i];
    __syncthreads();

    if (blockIdx.x == 0 && threadIdx.x < KK) {
        float s = 0.f;
        for (int d = 0; d < DD; ++d) { float v = cent[threadIdx.x * DD + d]; s += v * v; }
        c2out[c * KK + threadIdx.x] = s;
    }

    float acc[KK];
#pragma unroll
    for (int k = 0; k < KK; ++k) acc[k] = 0.f;
    const float* wbase = weight + (size_t)c * DD * OUT_F + o0 + lane_o;
#pragma unroll
    for (int chunk = 0; chunk < 8; ++chunk) {
        const int d = dg * 32 + chunk * 4;
        float w0 = wbase[(size_t)(d + 0) * OUT_F];
        float w1 = wbase[(size_t)(d + 1) * OUT_F];
        float w2 = wbase[(size_t)(d + 2) * OUT_F];
        float w3 = wbase[(size_t)(d + 3) * OUT_F];
#pragma unroll
        for (int k = 0; k < KK; ++k) {
            float4 cv = *(const float4*)(cent + k * DD + d);  // wave-uniform addr (broadcast)
            acc[k] += cv.x * w0 + cv.y * w1 + cv.z * w2 + cv.w * w3;
        }
    }
#pragma unroll
    for (int k = 0; k < KK; ++k) part[dg][k][lane_o] = acc[k];
    __syncthreads();
#pragma unroll
    for (int r = 0; r < 4; ++r) {
        int i = r * 256 + threadIdx.x;
        int k = i >> 6, o = i & 63;
        float s = part[0][k][o] + part[1][k][o] + part[2][k][o] + part[3][k][o];
        lut[((size_t)c * KK + k) * OUT_F + o0 + o] = s;
    }
}

// ---------------- K2: idx[t][c] = argmin_k (c2[c][k] - 2*dot(x[t,c,:], cent[c][k,:])) ----
// grid NTOK, block 256. thread = (k = tid/16, j = tid%16); cent reads fully coalesced.
__global__ __launch_bounds__(256) void idx_kernel(const float* __restrict__ x,
                                                  const float* __restrict__ centroids,
                                                  const float* __restrict__ c2,
                                                  unsigned char* __restrict__ idxout) {
    const int t = blockIdx.x;
    const int k = threadIdx.x >> 4;
    const int j = threadIdx.x & 15;
    __shared__ float xs[IN_F];          // 16 KB
    __shared__ float dproxy[NCB * KK];  // 2 KB

    {
        const float4* xg = (const float4*)(x + (size_t)t * IN_F);
        float4* xs4 = (float4*)xs;
        for (int i = threadIdx.x; i < IN_F / 4; i += 256) xs4[i] = xg[i];
    }
    __syncthreads();

    for (int c = 0; c < NCB; ++c) {
        // block covers cent[c] (8 KB) contiguously: lane byte-offset = tid*32
        const float4* cg = (const float4*)(centroids + ((size_t)c * KK + k) * DD + j * 8);
        float4 c0 = cg[0], c1 = cg[1];
        const float4* xv = (const float4*)(xs + c * DD + j * 8);
        float4 x0 = xv[0], x1 = xv[1];
        float dot = c0.x * x0.x + c0.y * x0.y + c0.z * x0.z + c0.w * x0.w
                  + c1.x * x1.x + c1.y * x1.y + c1.z * x1.z + c1.w * x1.w;
#pragma unroll
        for (int s = 1; s < 16; s <<= 1) dot += __shfl_xor(dot, s);
        if (j == 0) dproxy[c * KK + k] = c2[c * KK + k] - 2.f * dot;
    }
    __syncthreads();

    if (threadIdx.x < NCB) {
        const float* dp = dproxy + threadIdx.x * KK;
        float best = dp[0];
        int bi = 0;
#pragma unroll
        for (int kk = 1; kk < KK; ++kk) {
            float v = dp[kk];
            if (v < best) { best = v; bi = kk; }
        }
        idxout[(size_t)t * NCB + threadIdx.x] = (unsigned char)bi;
    }
}

// ---------------- K3: out[t][o] = bias[o] + sum_c lut[c][idx[t][c]][o] ------------------
// grid (NTOK/128, OUT_F/32) = (16, 64), block 256. LDS: lut o-slice 64 KB + idx tile 4 KB.
__global__ __launch_bounds__(256) void gather_kernel(const float* __restrict__ lut,
                                                     const unsigned char* __restrict__ idxb,
                                                     const float* __restrict__ bias,
                                                     float* __restrict__ out) {
    const int t0 = blockIdx.x * 128;
    const int o0 = blockIdx.y * 32;
    __shared__ float slut[NCB * KK * 32];     // 64 KB
    __shared__ unsigned char sidx[128 * NCB]; // 4 KB

    {
        // 512 rows x 32 floats; 8 threads per row (float4 each), 32 rows/pass
        const int row = threadIdx.x >> 3;
        const int q = threadIdx.x & 7;
        for (int r = row; r < NCB * KK; r += 32)
            ((float4*)(slut + r * 32))[q] = ((const float4*)(lut + (size_t)r * OUT_F + o0))[q];
    }
    {
        const int4* ig = (const int4*)(idxb + (size_t)t0 * NCB);
        int4* is4 = (int4*)sidx;
        if (threadIdx.x < 256) is4[threadIdx.x] = ig[threadIdx.x];  // 4 KB
    }
    __syncthreads();

    const int oo = (threadIdx.x & 15) * 2;  // float2 column pair
    const int tl = threadIdx.x >> 4;        // 16 token-groups per pass
    const float2 bv = *(const float2*)(bias + o0 + oo);

    for (int tt = tl; tt < 128; tt += 16) {
        float2 acc = bv;
        const unsigned int* ip = (const unsigned int*)(sidx + tt * NCB);
#pragma unroll
        for (int c4 = 0; c4 < NCB / 4; ++c4) {
            unsigned int iv4 = ip[c4];  // 4 packed indices, wave-broadcast
#pragma unroll
            for (int b = 0; b < 4; ++b) {
                int c = c4 * 4 + b;
                int iv = (iv4 >> (8 * b)) & 0xff;
                const float2 v = *(const float2*)(slut + (c * KK + iv) * 32 + oo);
                acc.x += v.x;
                acc.y += v.y;
            }
        }
        *(float2*)(out + (size_t)(t0 + tt) * OUT_F + o0 + oo) = acc;
    }
}

extern "C" void kernel_launch(void* const* d_in, const int* in_sizes, int n_in,
                              void* d_out, int out_size, void* d_ws, size_t ws_size,
                              hipStream_t stream) {
    const float* x         = (const float*)d_in[0];  // [2,1024,4096]
    const float* centroids = (const float*)d_in[1];  // [32,16,128]
    const float* weight    = (const float*)d_in[2];  // [32,128,2048]
    const float* bias      = (const float*)d_in[4];  // [2048]
    float* out = (float*)d_out;                      // [2048,2048] fp32

    float* lut = (float*)d_ws;                                        // 4 MB
    unsigned char* idxb = (unsigned char*)d_ws + (4u << 20);          // 64 KB
    float* c2 = (float*)((char*)d_ws + (4u << 20) + (64u << 10));     // 2 KB

    lut_kernel<<<dim3(OUT_F / 64, NCB), 256, 0, stream>>>(centroids, weight, lut, c2);
    idx_kernel<<<NTOK, 256, 0, stream>>>(x, centroids, c2, idxb);
    gather_kernel<<<dim3(NTOK / 128, OUT_F / 32), 256, 0, stream>>>(lut, idxb, bias, out);
}